// Round 20
// baseline (131.795 us; speedup 1.0000x reference)
//
#include <hip/hip_runtime.h>

#define D 128
#define GR 64               // GEMM rows per block
#define BN 64               // nodes per bucket (fill partition = reduce block)
#define NBIN 2048           // padded bin count for fill scan
#define SEB 8192            // edges per fill block
#define FTH 1024            // fill threads per block
#define BCAP 1280           // per-bucket capacity (mean 1024, +8 sigma)
#define CSTRIDE 16          // cursor padding (64B lines)

typedef __attribute__((ext_vector_type(8))) short bf16x8;
typedef __attribute__((ext_vector_type(4))) float f32x4;
typedef __attribute__((ext_vector_type(2))) float f32x2;
typedef __attribute__((ext_vector_type(4))) int   i32x4;
typedef __attribute__((ext_vector_type(4))) unsigned short u16x4;

__device__ __forceinline__ unsigned short bfrne(float f) {
    unsigned u = __float_as_uint(f);
    return (unsigned short)((u + 0x7FFFu + ((u >> 16) & 1u)) >> 16);
}

// ---------------- W prep: wt[c][k] = bf16(W[k][c]) ----------------
__global__ __launch_bounds__(256) void wprep_kernel(const float* __restrict__ w,
                                                    unsigned short* __restrict__ wt) {
    int t = blockIdx.x * 256 + threadIdx.x;   // t = c*128 + k
    int c = t >> 7, k = t & 127;
    wt[t] = bfrne(w[k * D + c]);
}

// ---------------- GEMM: hb = bf16(x @ W), pure-bf16 MFMA (unchanged) ----------------
__global__ __launch_bounds__(256) void gemm_kernel(const float* __restrict__ x,
                                                   const unsigned short* __restrict__ wt,
                                                   unsigned* __restrict__ hb2, int n) {
    __shared__ __align__(16) unsigned short ah[GR * D];  // 16 KB, swizzled

    int tid = threadIdx.x;
    int wid = tid >> 6, lane = tid & 63;
    int lr = lane & 15, lg = lane >> 4;
    int r0 = blockIdx.x * GR;

    char* ahb = (char*)ah;
    #pragma unroll
    for (int i = 0; i < 8; ++i) {
        int fe = (i << 10) + (tid << 2);
        int r = fe >> 7, k = fe & 127;
        f32x4 v = (f32x4){0.f, 0.f, 0.f, 0.f};
        if (r0 + r < n) v = __builtin_nontemporal_load((const f32x4*)(x + (size_t)(r0 + r) * D + k));
        u16x4 h;
        #pragma unroll
        for (int j = 0; j < 4; ++j) h[j] = bfrne(v[j]);
        int soff = (r << 8) + (((k << 1)) ^ ((r & 7) << 4));
        *(u16x4*)(ahb + soff) = h;
    }

    int ctb = wid * 2;
    bf16x8 Bh[2][4];
    #pragma unroll
    for (int c2 = 0; c2 < 2; ++c2) {
        #pragma unroll
        for (int ks = 0; ks < 4; ++ks) {
            size_t bo = (size_t)((ctb + c2) * 16 + lr) * D + ks * 32 + lg * 8;
            Bh[c2][ks] = *(const bf16x8*)(wt + bo);
        }
    }
    __syncthreads();

    f32x4 acc[4][2];
    #pragma unroll
    for (int rt = 0; rt < 4; ++rt)
        #pragma unroll
        for (int c2 = 0; c2 < 2; ++c2) acc[rt][c2] = (f32x4){0.f, 0.f, 0.f, 0.f};

    #pragma unroll
    for (int rt = 0; rt < 4; ++rt) {
        int row = rt * 16 + lr;
        int rbase = (row << 8);
        int rx = (row & 7) << 4;
        #pragma unroll
        for (int ks = 0; ks < 4; ++ks) {
            int kb = (ks << 6) + (lg << 4);
            bf16x8 Ah = *(const bf16x8*)(ahb + rbase + (kb ^ rx));
            #pragma unroll
            for (int c2 = 0; c2 < 2; ++c2) {
                acc[rt][c2] = __builtin_amdgcn_mfma_f32_16x16x32_bf16(Ah, Bh[c2][ks], acc[rt][c2], 0, 0, 0);
            }
        }
    }

    unsigned short* hbu = (unsigned short*)hb2;
    #pragma unroll
    for (int rt = 0; rt < 4; ++rt) {
        #pragma unroll
        for (int c2 = 0; c2 < 2; ++c2) {
            #pragma unroll
            for (int reg = 0; reg < 4; ++reg) {
                int rr = r0 + rt * 16 + lg * 4 + reg;
                if (rr < n) hbu[(size_t)rr * D + (ctb + c2) * 16 + lr] = bfrne(acc[rt][c2][reg]);
            }
        }
    }
}

// ---------------- fill3: LDS partition by 64-node bucket, 1024 threads ----------------
__global__ __launch_bounds__(FTH) void fill3_kernel(const int* __restrict__ row,
                                                    const int* __restrict__ col,
                                                    const float* __restrict__ ev,
                                                    int* __restrict__ gcur,
                                                    int2* __restrict__ pairs,
                                                    int e, int nsb) {
    __shared__ __align__(16) int2 sp[SEB];          // 64 KB, sorted (key,val)
    __shared__ unsigned short sup[SEB];             // 16 KB, bucket id per slot
    __shared__ int hist[NBIN];                      // 8 KB (becomes gbase after reserve)
    __shared__ int lcur[NBIN];                      // 8 KB

    int tid = threadIdx.x;
    int base = blockIdx.x * SEB;
    int cnt = e - base; if (cnt > SEB) cnt = SEB; if (cnt < 0) cnt = 0;

    for (int i = tid; i < NBIN; i += FTH) hist[i] = 0;
    __syncthreads();

    // pass 1: histogram of bucket ids (normal load -> row slice stays cached)
    #pragma unroll
    for (int j = 0; j < SEB / (FTH * 4); ++j) {
        int i0 = base + j * (FTH * 4) + tid * 4;
        if (i0 + 4 <= e) {
            i32x4 r = *(const i32x4*)(row + i0);
            #pragma unroll
            for (int k = 0; k < 4; ++k) atomicAdd(&hist[r[k] >> 6], 1);
        } else {
            for (int i = i0; i < e; ++i) atomicAdd(&hist[row[i] >> 6], 1);
        }
    }
    __syncthreads();

    // exclusive scan of NBIN bins (wave 0, carry loop)
    if (tid < 64) {
        int carry = 0;
        #pragma unroll
        for (int c = 0; c < NBIN / 64; ++c) {
            int i = c * 64 + tid;
            int v = hist[i];
            int s = v;
            #pragma unroll
            for (int d = 1; d < 64; d <<= 1) { int t = __shfl_up(s, d); if (tid >= d) s += t; }
            hist[i] = carry + s - v;
            carry += __shfl(s, 63);
        }
    }
    __syncthreads();
    for (int i = tid; i < NBIN; i += FTH) lcur[i] = hist[i];
    __syncthreads();

    // pass 2: rank & scatter into LDS (row cached; col/ev single-touch -> nt)
    #pragma unroll
    for (int j = 0; j < SEB / (FTH * 4); ++j) {
        int i0 = base + j * (FTH * 4) + tid * 4;
        if (i0 + 4 <= e) {
            i32x4 r = *(const i32x4*)(row + i0);
            i32x4 c = __builtin_nontemporal_load((const i32x4*)(col + i0));
            f32x4 v = __builtin_nontemporal_load((const f32x4*)(ev + i0));
            #pragma unroll
            for (int k = 0; k < 4; ++k) {
                int s = r[k] >> 6;
                int pos = atomicAdd(&lcur[s], 1);
                sp[pos] = make_int2(((r[k] & (BN - 1)) << 17) | c[k], __float_as_int(v[k]));
                sup[pos] = (unsigned short)s;
            }
        } else {
            for (int i = i0; i < e; ++i) {
                int s = row[i] >> 6;
                int pos = atomicAdd(&lcur[s], 1);
                sp[pos] = make_int2(((row[i] & (BN - 1)) << 17) | col[i], __float_as_int(ev[i]));
                sup[pos] = (unsigned short)s;
            }
        }
    }
    __syncthreads();

    // reserve one contiguous global range per non-empty bucket; hist[s] := gbase
    for (int s = tid; s < nsb; s += FTH) {
        int h0 = hist[s];
        int c = lcur[s] - h0;
        int gb = 0;
        if (c > 0) gb = atomicAdd(&gcur[s * CSTRIDE], c);
        hist[s] = gb - h0;    // gpos = hist[s] + idx
    }
    __syncthreads();

    // coalesced write-out (consecutive idx -> consecutive gpos within runs)
    for (int idx = tid; idx < cnt; idx += FTH) {
        int s = sup[idx];
        int gpos = hist[s] + idx;
        if (gpos < BCAP)
            pairs[(size_t)s * BCAP + gpos] = sp[idx];
    }
}

// ---------------- reduce7: own-bucket counting-sort + register gather-reduce ----------------
__global__ __launch_bounds__(256) void reduce7_kernel(const unsigned* __restrict__ hb2,
                                                      const int2* __restrict__ pairs,
                                                      const int* __restrict__ gcur,
                                                      const float2* __restrict__ bias2,
                                                      float2* __restrict__ out2, int n) {
    __shared__ __align__(16) int2 sp[BCAP];   // 10 KB sorted (col,val)
    __shared__ int hist[BN + 1];
    __shared__ int bcur[BN];

    int b = blockIdx.x;
    int tid = threadIdx.x;
    int lane = tid & 63, wid = tid >> 6;

    int cnt = gcur[b * CSTRIDE]; if (cnt > BCAP) cnt = BCAP;
    const int2* pb = pairs + (size_t)b * BCAP;

    if (tid < BN) hist[tid] = 0;
    __syncthreads();

    for (int j = tid; j < cnt; j += 256) atomicAdd(&hist[pb[j].x >> 17], 1);
    __syncthreads();

    if (tid < BN) {
        int v = hist[tid];
        int s = v;
        #pragma unroll
        for (int d = 1; d < BN; d <<= 1) { int t = __shfl_up(s, d); if (lane >= d) s += t; }
        int ex = s - v;
        hist[tid] = ex; bcur[tid] = ex;
        if (tid == BN - 1) hist[BN] = s;   // == cnt
    }
    __syncthreads();

    for (int j = tid; j < cnt; j += 256) {
        int2 p = pb[j];
        int rl = p.x >> 17;
        int pos = atomicAdd(&bcur[rl], 1);
        sp[pos] = make_int2(p.x & 0x1FFFF, p.y);
    }
    __syncthreads();

    int node0 = b * BN;
    for (int r = wid; r < BN; r += 4) {
        int node = node0 + r;
        if (node >= n) break;
        int beg = hist[r], end = hist[r + 1];
        float2 acc = {0.f, 0.f};
        int j = beg;
        for (; j + 8 <= end; j += 8) {
            unsigned u[8]; float v[8];
            #pragma unroll
            for (int k = 0; k < 8; ++k) {
                int2 p = sp[j + k];
                v[k] = __int_as_float(p.y);
                u[k] = hb2[(size_t)p.x * 64 + lane];
            }
            #pragma unroll
            for (int k = 0; k < 8; ++k) {
                acc.x += v[k] * __uint_as_float(u[k] << 16);
                acc.y += v[k] * __uint_as_float(u[k] & 0xFFFF0000u);
            }
        }
        for (; j < end; ++j) {
            int2 p = sp[j];
            float v = __int_as_float(p.y);
            unsigned u = hb2[(size_t)p.x * 64 + lane];
            acc.x += v * __uint_as_float(u << 16);
            acc.y += v * __uint_as_float(u & 0xFFFF0000u);
        }
        float2 bb = bias2[lane];
        f32x2 o = (f32x2){acc.x + bb.x, acc.y + bb.y};
        __builtin_nontemporal_store(o, (f32x2*)&out2[(size_t)node * 64 + lane]);
    }
}

extern "C" void kernel_launch(void* const* d_in, const int* in_sizes, int n_in,
                              void* d_out, int out_size, void* d_ws, size_t ws_size,
                              hipStream_t stream) {
    const float* x    = (const float*)d_in[0];
    const float* w    = (const float*)d_in[1];
    const float* bias = (const float*)d_in[2];
    const float* ev   = (const float*)d_in[3];
    const int*   row  = (const int*)d_in[4];
    const int*   col  = (const int*)d_in[5];
    float* out = (float*)d_out;

    int n = in_sizes[0] / D;   // 100000
    int e = in_sizes[3];       // 1600000
    int nsb = (n + BN - 1) / BN;   // 1563 buckets

    // workspace layout
    unsigned* hb2   = (unsigned*)d_ws;                         // n*64 uints (25.6 MB)
    int2*     pairs = (int2*)(hb2 + (size_t)n * 64);           // nsb*BCAP int2 (16 MB)
    int*      gcur  = (int*)(pairs + (size_t)nsb * BCAP);      // nsb*CSTRIDE ints (100 KB)
    unsigned short* wt = (unsigned short*)(gcur + (size_t)nsb * CSTRIDE); // 32 KB

    hipMemsetAsync(gcur, 0, (size_t)nsb * CSTRIDE * sizeof(int), stream);

    wprep_kernel<<<(D * D) / 256, 256, 0, stream>>>(w, wt);
    gemm_kernel<<<(n + GR - 1) / GR, 256, 0, stream>>>(x, wt, hb2, n);
    fill3_kernel<<<(e + SEB - 1) / SEB, FTH, 0, stream>>>(row, col, ev, gcur, pairs, e, nsb);
    reduce7_kernel<<<nsb, 256, 0, stream>>>(hb2, pairs, gcur,
                                            (const float2*)bias, (float2*)out, n);
}

// Round 21
// 120.343 us; speedup vs baseline: 1.0952x; 1.0952x over previous
//
#include <hip/hip_runtime.h>

#define D 128
#define GR 128              // GEMM rows per block
#define SN 128              // nodes per super-bucket (fill partition)
#define NSUPB 1024          // padded bin count for fill2 scan
#define SEB 8192            // edges per fill2 block
#define FTH 1024            // fill2 threads per block
#define SUPCAP 2432         // per-super capacity (mean 2046, ~+8.5 sigma)
#define HCAP 1408           // per-half-super LDS sort capacity (mean 1023)
#define CSTRIDE 16          // cursor padding (64B lines)

typedef __attribute__((ext_vector_type(8))) short bf16x8;
typedef __attribute__((ext_vector_type(4))) float f32x4;
typedef __attribute__((ext_vector_type(2))) float f32x2;
typedef __attribute__((ext_vector_type(4))) int   i32x4;
typedef __attribute__((ext_vector_type(4))) unsigned short u16x4;

__device__ __forceinline__ unsigned short bfrne(float f) {
    unsigned u = __float_as_uint(f);
    return (unsigned short)((u + 0x7FFFu + ((u >> 16) & 1u)) >> 16);
}

// ---------------- W prep: wt[c][k] = bf16(W[k][c]); also zero gcur ----------------
__global__ __launch_bounds__(256) void wprep_kernel(const float* __restrict__ w,
                                                    unsigned short* __restrict__ wt,
                                                    int* __restrict__ gcur, int gcn) {
    int t = blockIdx.x * 256 + threadIdx.x;   // t = c*128 + k
    int c = t >> 7, k = t & 127;
    wt[t] = bfrne(w[k * D + c]);
    for (int i = t; i < gcn; i += D * D) gcur[i] = 0;
}

// ---------------- GEMM: hb = bf16(x @ W), pure-bf16 MFMA, 128-row tile ----------------
__global__ __launch_bounds__(256) void gemm_kernel(const float* __restrict__ x,
                                                   const unsigned short* __restrict__ wt,
                                                   unsigned* __restrict__ hb2, int n) {
    __shared__ __align__(16) unsigned short ah[GR * D];  // 32 KB, swizzled

    int tid = threadIdx.x;
    int wid = tid >> 6, lane = tid & 63;
    int lr = lane & 15, lg = lane >> 4;
    int r0 = blockIdx.x * GR;

    char* ahb = (char*)ah;
    #pragma unroll
    for (int i = 0; i < GR * D / 1024; ++i) {
        int fe = (i << 10) + (tid << 2);
        int r = fe >> 7, k = fe & 127;
        f32x4 v = (f32x4){0.f, 0.f, 0.f, 0.f};
        if (r0 + r < n) v = __builtin_nontemporal_load((const f32x4*)(x + (size_t)(r0 + r) * D + k));
        u16x4 h;
        #pragma unroll
        for (int j = 0; j < 4; ++j) h[j] = bfrne(v[j]);
        int soff = (r << 8) + (((k << 1)) ^ ((r & 7) << 4));
        *(u16x4*)(ahb + soff) = h;
    }

    int ctb = wid * 2;
    bf16x8 Bh[2][4];
    #pragma unroll
    for (int c2 = 0; c2 < 2; ++c2) {
        #pragma unroll
        for (int ks = 0; ks < 4; ++ks) {
            size_t bo = (size_t)((ctb + c2) * 16 + lr) * D + ks * 32 + lg * 8;
            Bh[c2][ks] = *(const bf16x8*)(wt + bo);
        }
    }
    __syncthreads();

    f32x4 acc[GR / 16][2];
    #pragma unroll
    for (int rt = 0; rt < GR / 16; ++rt)
        #pragma unroll
        for (int c2 = 0; c2 < 2; ++c2) acc[rt][c2] = (f32x4){0.f, 0.f, 0.f, 0.f};

    #pragma unroll
    for (int rt = 0; rt < GR / 16; ++rt) {
        int row = rt * 16 + lr;
        int rbase = (row << 8);
        int rx = (row & 7) << 4;
        #pragma unroll
        for (int ks = 0; ks < 4; ++ks) {
            int kb = (ks << 6) + (lg << 4);
            bf16x8 Ah = *(const bf16x8*)(ahb + rbase + (kb ^ rx));
            #pragma unroll
            for (int c2 = 0; c2 < 2; ++c2) {
                acc[rt][c2] = __builtin_amdgcn_mfma_f32_16x16x32_bf16(Ah, Bh[c2][ks], acc[rt][c2], 0, 0, 0);
            }
        }
    }

    unsigned short* hbu = (unsigned short*)hb2;
    #pragma unroll
    for (int rt = 0; rt < GR / 16; ++rt) {
        #pragma unroll
        for (int c2 = 0; c2 < 2; ++c2) {
            #pragma unroll
            for (int reg = 0; reg < 4; ++reg) {
                int rr = r0 + rt * 16 + lg * 4 + reg;
                if (rr < n) hbu[(size_t)rr * D + (ctb + c2) * 16 + lr] = bfrne(acc[rt][c2][reg]);
            }
        }
    }
}

// ---------------- fill2: LDS-staged partition, 1024 threads/block ----------------
__global__ __launch_bounds__(FTH) void fill2_kernel(const int* __restrict__ row,
                                                    const int* __restrict__ col,
                                                    const float* __restrict__ ev,
                                                    int* __restrict__ gcur,
                                                    int2* __restrict__ pairs,
                                                    int e, int nsup) {
    __shared__ __align__(16) int2 sp[SEB];          // 64 KB, sorted (key,val)
    __shared__ unsigned short sup[SEB];             // 16 KB, super id per slot
    __shared__ int hist[NSUPB];                     // 4 KB
    __shared__ int lcur[NSUPB];                     // 4 KB
    __shared__ int gbase[NSUPB];                    // 4 KB

    int tid = threadIdx.x;
    int base = blockIdx.x * SEB;
    int cnt = e - base; if (cnt > SEB) cnt = SEB; if (cnt < 0) cnt = 0;

    for (int i = tid; i < NSUPB; i += FTH) hist[i] = 0;
    __syncthreads();

    // pass 1: histogram of super ids (normal load -> row slice stays cached)
    #pragma unroll
    for (int j = 0; j < SEB / (FTH * 4); ++j) {
        int i0 = base + j * (FTH * 4) + tid * 4;
        if (i0 + 4 <= e) {
            i32x4 r = *(const i32x4*)(row + i0);
            #pragma unroll
            for (int k = 0; k < 4; ++k) atomicAdd(&hist[r[k] >> 7], 1);
        } else {
            for (int i = i0; i < e; ++i) atomicAdd(&hist[row[i] >> 7], 1);
        }
    }
    __syncthreads();

    // exclusive scan of NSUPB bins (wave 0, carry loop)
    if (tid < 64) {
        int carry = 0;
        #pragma unroll
        for (int c = 0; c < NSUPB / 64; ++c) {
            int i = c * 64 + tid;
            int v = hist[i];
            int s = v;
            #pragma unroll
            for (int d = 1; d < 64; d <<= 1) { int t = __shfl_up(s, d); if (tid >= d) s += t; }
            hist[i] = carry + s - v;
            carry += __shfl(s, 63);
        }
    }
    __syncthreads();
    for (int i = tid; i < NSUPB; i += FTH) lcur[i] = hist[i];
    __syncthreads();

    // pass 2: rank & scatter into LDS (row cached; col/ev single-touch -> nt)
    #pragma unroll
    for (int j = 0; j < SEB / (FTH * 4); ++j) {
        int i0 = base + j * (FTH * 4) + tid * 4;
        if (i0 + 4 <= e) {
            i32x4 r = *(const i32x4*)(row + i0);
            i32x4 c = __builtin_nontemporal_load((const i32x4*)(col + i0));
            f32x4 v = __builtin_nontemporal_load((const f32x4*)(ev + i0));
            #pragma unroll
            for (int k = 0; k < 4; ++k) {
                int s = r[k] >> 7;
                int pos = atomicAdd(&lcur[s], 1);
                sp[pos] = make_int2(((r[k] & (SN - 1)) << 17) | c[k], __float_as_int(v[k]));
                sup[pos] = (unsigned short)s;
            }
        } else {
            for (int i = i0; i < e; ++i) {
                int s = row[i] >> 7;
                int pos = atomicAdd(&lcur[s], 1);
                sp[pos] = make_int2(((row[i] & (SN - 1)) << 17) | col[i], __float_as_int(ev[i]));
                sup[pos] = (unsigned short)s;
            }
        }
    }
    __syncthreads();

    // reserve one contiguous global range per non-empty super
    for (int s = tid; s < nsup; s += FTH) {
        int c = lcur[s] - hist[s];
        int gb = 0;
        if (c > 0) gb = atomicAdd(&gcur[s * CSTRIDE], c);
        gbase[s] = gb - hist[s];    // gpos = gbase[s] + idx
    }
    __syncthreads();

    // coalesced write-out (consecutive idx -> consecutive gpos within runs)
    for (int idx = tid; idx < cnt; idx += FTH) {
        int s = sup[idx];
        int gpos = gbase[s] + idx;
        if (gpos < SUPCAP)
            pairs[(size_t)s * SUPCAP + gpos] = sp[idx];
    }
}

// ---------------- reduce3: half-super counting-sort + register gather-reduce ----------------
__global__ __launch_bounds__(256) void reduce3_kernel(const unsigned* __restrict__ hb2,
                                                      const int2* __restrict__ pairs,
                                                      const int* __restrict__ gcur,
                                                      const float2* __restrict__ bias2,
                                                      float2* __restrict__ out2, int n) {
    __shared__ __align__(16) int2 sp[HCAP];   // 11 KB sorted (col,val), own half only
    __shared__ int hist[65];
    __shared__ int bcur[64];

    int b = blockIdx.x;
    int sup = b >> 1, half = b & 1;
    int tid = threadIdx.x;
    int lane = tid & 63, wid = tid >> 6;

    int cnt = gcur[sup * CSTRIDE]; if (cnt > SUPCAP) cnt = SUPCAP;
    const int2* pb = pairs + (size_t)sup * SUPCAP;

    if (tid < 64) hist[tid] = 0;
    __syncthreads();

    for (int j = tid; j < cnt; j += 256) {
        int rl = pb[j].x >> 17;
        if ((rl >> 6) == half) atomicAdd(&hist[rl & 63], 1);
    }
    __syncthreads();

    if (tid < 64) {
        int v = hist[tid];
        int s = v;
        #pragma unroll
        for (int d = 1; d < 64; d <<= 1) { int t = __shfl_up(s, d); if (lane >= d) s += t; }
        int ex = s - v;
        hist[tid] = ex; bcur[tid] = ex;
        if (tid == 63) hist[64] = s > HCAP ? HCAP : s;
    }
    __syncthreads();

    for (int j = tid; j < cnt; j += 256) {
        int2 p = pb[j];
        int rl = p.x >> 17;
        if ((rl >> 6) == half) {
            int pos = atomicAdd(&bcur[rl & 63], 1);
            if (pos < HCAP) sp[pos] = make_int2(p.x & 0x1FFFF, p.y);
        }
    }
    __syncthreads();

    int node0 = sup * SN + half * 64;
    for (int r = wid; r < 64; r += 4) {
        int node = node0 + r;
        if (node >= n) break;
        int beg = hist[r], end = hist[r + 1];
        if (beg > HCAP) beg = HCAP;
        if (end > HCAP) end = HCAP;
        float2 acc = {0.f, 0.f};
        int j = beg;
        for (; j + 8 <= end; j += 8) {
            unsigned u[8]; float v[8];
            #pragma unroll
            for (int k = 0; k < 8; ++k) {
                int2 p = sp[j + k];
                v[k] = __int_as_float(p.y);
                u[k] = hb2[(size_t)p.x * 64 + lane];
            }
            #pragma unroll
            for (int k = 0; k < 8; ++k) {
                acc.x += v[k] * __uint_as_float(u[k] << 16);
                acc.y += v[k] * __uint_as_float(u[k] & 0xFFFF0000u);
            }
        }
        for (; j < end; ++j) {
            int2 p = sp[j];
            float v = __int_as_float(p.y);
            unsigned u = hb2[(size_t)p.x * 64 + lane];
            acc.x += v * __uint_as_float(u << 16);
            acc.y += v * __uint_as_float(u & 0xFFFF0000u);
        }
        float2 bb = bias2[lane];
        f32x2 o = (f32x2){acc.x + bb.x, acc.y + bb.y};
        __builtin_nontemporal_store(o, (f32x2*)&out2[(size_t)node * 64 + lane]);
    }
}

extern "C" void kernel_launch(void* const* d_in, const int* in_sizes, int n_in,
                              void* d_out, int out_size, void* d_ws, size_t ws_size,
                              hipStream_t stream) {
    const float* x    = (const float*)d_in[0];
    const float* w    = (const float*)d_in[1];
    const float* bias = (const float*)d_in[2];
    const float* ev   = (const float*)d_in[3];
    const int*   row  = (const int*)d_in[4];
    const int*   col  = (const int*)d_in[5];
    float* out = (float*)d_out;

    int n = in_sizes[0] / D;   // 100000
    int e = in_sizes[3];       // 1600000
    int nsup = (n + SN - 1) / SN;   // 782 super-buckets

    // workspace layout
    unsigned* hb2   = (unsigned*)d_ws;                         // n*64 uints (25.6 MB)
    int2*     pairs = (int2*)(hb2 + (size_t)n * 64);           // nsup*SUPCAP int2 (15.2 MB)
    int*      gcur  = (int*)(pairs + (size_t)nsup * SUPCAP);   // nsup*CSTRIDE ints (50 KB)
    unsigned short* wt = (unsigned short*)(gcur + (size_t)nsup * CSTRIDE); // 32 KB

    wprep_kernel<<<(D * D) / 256, 256, 0, stream>>>(w, wt, gcur, nsup * CSTRIDE);
    gemm_kernel<<<(n + GR - 1) / GR, 256, 0, stream>>>(x, wt, hb2, n);
    fill2_kernel<<<(e + SEB - 1) / SEB, FTH, 0, stream>>>(row, col, ev, gcur, pairs, e, nsup);
    reduce3_kernel<<<nsup * 2, 256, 0, stream>>>(hb2, pairs, gcur,
                                                 (const float2*)bias, (float2*)out, n);
}